// Round 9
// baseline (855.114 us; speedup 1.0000x reference)
//
#include <hip/hip_runtime.h>
#include <math.h>

// Problem constants
#define CC 62
#define TT 2000
#define BB 256
#define VECN 1953          // C*(C+1)/2
#define HID 64
#define NCLS 3
#define LDX 68             // x-tile row stride (floats)
#define XBUF (64 * LDX)    // floats per x-tile buffer (4352)
#define NT1 32             // ceil(TT / 64)
#define SLD 64             // S row stride (doubles)
#define LDGF 68            // fp32 G column stride (floats, 272B -> 16B aligned)

typedef const unsigned int __attribute__((address_space(1)))* gbl_u32p;
typedef unsigned int __attribute__((address_space(3)))* lds_u32p;

#define WAITV(n) asm volatile("s_waitcnt vmcnt(" #n ")" ::: "memory")

__device__ __forceinline__ void decodePi(int pi, int& i, int& j)
{
    int ii = 0, rem = pi;
    while (rem >= CC - ii) { rem -= (CC - ii); ++ii; }
    i = ii; j = ii + rem;
}

// ---------------------------------------------------------------------------
// FUSED (round 9): Grammian -> cov -> A=WCW^T+epsI -> REGISTER-RESIDENT
// one-wave Jacobi -> log-map -> triu-vec -> MLP head. grid=B, block=512.
//
// Round-8 analysis: Jacobi round = ~1650 cy but pipe work only ~490 cy; the
// rest is the per-round 9-wave barrier + lockstep-exposed LDS latency.
// THIS ROUND removes the barrier entirely: lane c of wave 0 owns COLUMN c
// of G in registers (64 fp32; rows 62/63 = 0). Per round: partner via
// circle-method arithmetic (verified vs pairPQ), partner column via 64
// __shfl (bpermute), d computed fully lane-locally (products commute ->
// lanes p,q bitwise-agree; no reduce), rotation in registers, own norm
// (fp64) updated locally, partner norm via 1 shuffle. Convergence via
// __any. No barriers, no G LDS traffic, no pair table in the sweep loop.
//
// Block 576->512 (8 waves, 2/SIMD): VGPR budget 256 covers the Jacobi
// wave's g[64]+pv[64]+temps (~160) without spill (round-7 lesson: a 9-wave
// block would cap VGPR at ~170 and spill). Phase A remapped to 2-way
// t-split (136 pairs x 2 lanes); WCW to 8-column chunks (round-0-proven).
//
// LDS overlays: sA region hosts sX(34816B) -> sS(32768B) -> sGf(16864B);
// sC(15624B) -> sVec. ~55.8KB static.
// ---------------------------------------------------------------------------
__global__ __launch_bounds__(512) void fused(
    const float* __restrict__ x, const float* __restrict__ cw,
    const float* __restrict__ pw, const float* __restrict__ pbias,
    const float* __restrict__ hw, const float* __restrict__ hb,
    float* __restrict__ out)
{
    const int b = blockIdx.x, tid = threadIdx.x;
    const int wid = tid >> 6, lane = tid & 63;

    __shared__ __align__(16) double sA[4352];   // 34816 B: sX | sS | sGf
    __shared__ __align__(16) double sC[VECN];   // 15624 B: cov | sVec
    __shared__ double sU[8 * 64];
    __shared__ double sD[64];
    __shared__ double sMean[64];
    __shared__ float  sF[HID];

    float*  sX   = reinterpret_cast<float*>(sA);
    double* sS   = sA;
    float*  sGf  = reinterpret_cast<float*>(sA);   // overlays dead sS
    float*  sVec = reinterpret_cast<float*>(sC);

    // ---------------- Phase A: Grammian (4x4 tiles, 2-way t-split) ----------
    const int slot = tid >> 1, ksA = tid & 1;
    const bool actA = (slot < 136);
    int gi = 0, gj = 0;
    if (actA) {
        int g2 = 0, rem = slot;
        while (rem >= 16 - g2) { rem -= (16 - g2); ++g2; }
        gi = g2; gj = g2 + rem;
    }
    const int a0 = 4 * gi, b0 = 4 * gj;
    const int pA = gi >> 1, pB = gj >> 1;   // (4g+r)>>3 for r<4

    double acc[4][4];
    float  accf[4][4];
#pragma unroll
    for (int r = 0; r < 4; ++r)
#pragma unroll
        for (int c = 0; c < 4; ++c) { acc[r][c] = 0.0; accf[r][c] = 0.0f; }

    // pad rows: 62 = ones (mean trick), 63 = zero; both buffers, once.
    if (tid < 128) {
        int bu = tid >> 6, t = tid & 63;
        sX[bu * XBUF + 62 * LDX + t] = 1.0f;
        sX[bu * XBUF + 63 * LDX + t] = 0.0f;
    }
    __syncthreads();

    const float* xb = x + (size_t)b * (CC * TT);

    // DMA one tile: wave w issues rows c = w, w+8, ... (w<6: 8 rows, else 7).
    // Global source chunk-XOR pre-swizzled (p(c)=c>>3); LDS dest linear.
    auto issueTile = [&](int buf, int tile) {
        const int t0 = tile * 64;
        for (int c = wid; c < CC; c += 8) {
            const int ps = c >> 3;
            const int tt = 4 * ((lane >> 2) ^ ps) + (lane & 3);
            if (t0 + tt < TT) {
                const float* gp = xb + (size_t)c * TT + t0 + tt;
                __builtin_amdgcn_global_load_lds(
                    (gbl_u32p)gp, (lds_u32p)&sX[buf * XBUF + c * LDX], 4, 0, 0);
            }
        }
    };

    issueTile(0, 0);
    for (int tile = 0; tile < NT1; ++tile) {
        const int cur = tile & 1;
        __builtin_amdgcn_s_barrier();        // prev compute done: buf cur^1 free
        if (tile + 1 < NT1) {
            issueTile(cur ^ 1, tile + 1);
            if (wid < 6) WAITV(8); else WAITV(7);   // cur-tile loads landed
        } else {
            WAITV(0);
        }
        __builtin_amdgcn_sched_barrier(0);
        __builtin_amdgcn_s_barrier();        // all waves' cur loads visible
        if (actA) {
            const float* xt = &sX[cur * XBUF];
            const int nqm = min(16, (TT - tile * 64) >> 2);
            for (int m = ksA; m < nqm; m += 2) {
                const int ca = 4 * (m ^ pA), cb = 4 * (m ^ pB);
                float4 af[4], bf[4];
#pragma unroll
                for (int r = 0; r < 4; ++r)
                    af[r] = *reinterpret_cast<const float4*>(&xt[(a0 + r) * LDX + ca]);
#pragma unroll
                for (int r = 0; r < 4; ++r)
                    bf[r] = *reinterpret_cast<const float4*>(&xt[(b0 + r) * LDX + cb]);
#pragma unroll
                for (int k = 0; k < 4; ++k) {
#pragma unroll
                    for (int r = 0; r < 4; ++r)
#pragma unroll
                        for (int s = 0; s < 4; ++s)
                            accf[r][s] += (&af[r].x)[k] * (&bf[s].x)[k];
                }
            }
            // per-tile fp64 promotion (<=16 fp32 products per partial)
#pragma unroll
            for (int r = 0; r < 4; ++r)
#pragma unroll
                for (int c = 0; c < 4; ++c) {
                    acc[r][c] += (double)accf[r][c];
                    accf[r][c] = 0.0f;
                }
        }
    }

    // 2-way t-split reduce (registers only), then sS overlay of sX
#pragma unroll
    for (int r = 0; r < 4; ++r)
#pragma unroll
        for (int c = 0; c < 4; ++c)
            acc[r][c] += __shfl_xor(acc[r][c], 1, 2);
    __syncthreads();                 // all sX reads complete before overlay
    if (actA && ksA == 0) {
#pragma unroll
        for (int r = 0; r < 4; ++r)
#pragma unroll
            for (int c = 0; c < 4; ++c)
                sS[(a0 + r) * SLD + (b0 + c)] = acc[r][c];
    }
    __syncthreads();

    // ---------------- Phase B: cov -> A(fp32) ----------------
    if (tid < CC) sMean[tid] = sS[tid * SLD + 62] / (double)TT;
    __syncthreads();

    // packed cov_x = (S - T m m^T)/(T-1)
    for (int pi = tid; pi < VECN; pi += 512) {
        int i, j; decodePi(pi, i, j);
        sC[pi] = (sS[i * SLD + j] - (double)TT * sMean[i] * sMean[j]) / 1999.0;
    }
    __syncthreads();

    // sS dead -> zero fp32 sGf (overlay); also rows 62/63 of every column
    for (int e = tid; e < CC * LDGF; e += 512) sGf[e] = 0.0f;
    __syncthreads();

    // A = W C W^T + eps I, chunks of 8 output columns; store fp32
    const int jj = tid >> 6, kk = tid & 63;
    for (int j0 = 0; j0 < CC; j0 += 8) {
        const int j = j0 + jj;
        if (kk < CC && j < CC) {
            const float* wr = cw + j * CC;
            double a = 0.0; int idx = kk;
            for (int l = 0; l < kk; ++l) { a += sC[idx] * (double)wr[l]; idx += 61 - l; }
            for (int l = kk; l < CC; ++l) { a += sC[idx] * (double)wr[l]; idx += 1; }
            sU[jj * 64 + kk] = a;    // u_j[k] = (C w_j)[k]
        }
        __syncthreads();
        const int i = kk;
        if (i < CC && j < CC && i <= j) {
            const float* wi = cw + i * CC;
            double a = (i == j) ? 1e-3 : 0.0;
            for (int l = 0; l < CC; ++l) a += (double)wi[l] * sU[jj * 64 + l];
            sGf[j * LDGF + i] = (float)a;
            sGf[i * LDGF + j] = (float)a;
        }
        __syncthreads();
    }

    // ---------------- Jacobi: single wave, register-resident ----------------
    if (wid == 0 && lane < CC) {
        float g[64], pv[64];
#pragma unroll
        for (int k = 0; k < 16; ++k) {
            float4 v = *reinterpret_cast<const float4*>(&sGf[lane * LDGF + 4 * k]);
            g[4 * k] = v.x; g[4 * k + 1] = v.y; g[4 * k + 2] = v.z; g[4 * k + 3] = v.w;
        }
        double n = 0.0;
#pragma unroll
        for (int k = 0; k < 64; ++k) n = fma((double)g[k], (double)g[k], n);

        for (int sweep = 0; sweep < 20; ++sweep) {
            int flagAny = 0;
            for (int r = 0; r < 61; ++r) {
                // circle-method partner of column `lane` at round r
                int partner;
                if (lane == 0) partner = 1 + (r + 60) % 61;
                else {
                    int a2 = (lane - 1 - r + 61) % 61;
                    partner = (a2 == 60) ? 0 : 1 + (r + 59 - a2) % 61;
                }
                const bool isP = lane < partner;
                // partner column via bpermute (only LDS-pipe use per round)
#pragma unroll
                for (int k = 0; k < 64; ++k) pv[k] = __shfl(g[k], partner);
                // lane-local dot: lanes p,q bitwise-agree (products commute,
                // identical summation order)
                float d0 = 0.f, d1 = 0.f, d2f = 0.f, d3 = 0.f;
#pragma unroll
                for (int k = 0; k < 64; k += 4) {
                    d0 = fmaf(g[k],     pv[k],     d0);
                    d1 = fmaf(g[k + 1], pv[k + 1], d1);
                    d2f = fmaf(g[k + 2], pv[k + 2], d2f);
                    d3 = fmaf(g[k + 3], pv[k + 3], d3);
                }
                float df = (d0 + d1) + (d2f + d3);
                double npart = __shfl(n, partner);
                double np = isP ? n : npart, nq2 = isP ? npart : n;
                double dd = (double)df, d2 = dd * dd, bb = np * nq2;
                if (d2 > bb * 1e-12) {
                    float npf = (float)np, nqf = (float)nq2;
                    float thf = (nqf - npf) * __builtin_amdgcn_rcpf(2.0f * df);
                    float a3 = fabsf(thf);
                    float tf = __builtin_amdgcn_rcpf(
                        a3 + __builtin_amdgcn_sqrtf(fmaf(a3, a3, 1.0f)));
                    if (thf < 0.0f) tf = -tf;
                    float cf = __builtin_amdgcn_rsqf(fmaf(tf, tf, 1.0f));
                    float sn = tf * cf;
                    float ss = isP ? -sn : sn;   // p: c*gp - s*gq ; q: s*gp + c*gq
#pragma unroll
                    for (int k = 0; k < 64; ++k)
                        g[k] = fmaf(cf, g[k], ss * pv[k]);
                    double td = (double)tf * dd;
                    n += isP ? -td : td;
                    if (d2 > bb * 1e-9) flagAny = 1;
                }
            }
            if (!__any(flagAny)) break;
        }

        // write back; exact fp64 norm from final registers -> sD
#pragma unroll
        for (int k = 0; k < 16; ++k) {
            float4 v = make_float4(g[4 * k], g[4 * k + 1], g[4 * k + 2], g[4 * k + 3]);
            *reinterpret_cast<float4*>(&sGf[lane * LDGF + 4 * k]) = v;
        }
        double nf = 0.0;
#pragma unroll
        for (int k = 0; k < 64; ++k) nf = fma((double)g[k], (double)g[k], nf);
        double lamv = sqrt(nf);
        sD[lane] = log(fmax(lamv, 1e-6)) / nf;
    }
    __syncthreads();

    // triu vectorization into LDS (sVec overlays dead sC)
    for (int pi = tid; pi < VECN; pi += 512) {
        int i, j; decodePi(pi, i, j);
        double a = 0.0;
        for (int k2 = 0; k2 < CC; ++k2)
            a += sD[k2] * (double)sGf[k2 * LDGF + i] * (double)sGf[k2 * LDGF + j];
        sVec[pi] = (float)a;
    }
    __syncthreads();

    // ---------------- Phase C: MLP head ----------------
    {
        for (int hh = 0; hh < 8; ++hh) {
            const int h = wid * 8 + hh;
            const float* w = pw + (size_t)h * VECN;
            float a = 0.0f;
            for (int k = lane; k < VECN; k += 64) a += sVec[k] * w[k];
            a += __shfl_xor(a, 32); a += __shfl_xor(a, 16); a += __shfl_xor(a, 8);
            a += __shfl_xor(a, 4);  a += __shfl_xor(a, 2);  a += __shfl_xor(a, 1);
            if (lane == 0) sF[h] = fmaxf(a + pbias[h], 0.0f);
        }
    }
    __syncthreads();
    if (tid < NCLS) {
        float o = hb[tid];
        for (int hh = 0; hh < HID; ++hh) o += sF[hh] * hw[tid * HID + hh];
        out[b * NCLS + tid] = o;
    }
}

// ---------------------------------------------------------------------------
extern "C" void kernel_launch(void* const* d_in, const int* in_sizes, int n_in,
                              void* d_out, int out_size, void* d_ws, size_t ws_size,
                              hipStream_t stream)
{
    const float* x  = (const float*)d_in[0];
    const float* cw = (const float*)d_in[1];
    // d_in[2] = conv bias: cancels in covariance, unused
    const float* pw = (const float*)d_in[3];
    const float* pb = (const float*)d_in[4];
    const float* hw = (const float*)d_in[5];
    const float* hb = (const float*)d_in[6];
    float* out = (float*)d_out;

    // single fused dispatch; workspace unused
    fused<<<BB, 512, 0, stream>>>(x, cw, pw, pb, hw, hb, out);
}